// Round 2
// baseline (209.605 us; speedup 1.0000x reference)
//
#include <hip/hip_runtime.h>

// Problem constants (CrossAttention_73856257622246)
#define NB 4      // batch
#define QC 256    // query channels
#define SD 16384  // Z*H*W spatial per batch
#define NT 256    // tokens
#define KVC 512   // token channels
#define TC 128    // TOKEN_CH
#define NH 4      // heads
#define DH 32     // head dim
#define TSP 64    // spatial tile per block

typedef unsigned short u16;
typedef unsigned int u32;
typedef __attribute__((ext_vector_type(8))) short bf16x8;  // MFMA A/B frag (4 VGPR)
typedef __attribute__((ext_vector_type(4))) float f32x4;   // MFMA C/D frag

__device__ __forceinline__ float b2f(u16 u) {
  unsigned int v = ((unsigned int)u) << 16;
  return __builtin_bit_cast(float, v);
}
__device__ __forceinline__ u16 f2b(float f) {  // RNE (used in cold paths / packing)
  unsigned int x = __builtin_bit_cast(unsigned int, f);
  unsigned int r = (x + 0x7fffu + ((x >> 16) & 1u)) >> 16;
  return (u16)r;
}
__device__ __forceinline__ u16 f2b_fast(float f) {  // round-half-up, 2 VALU
  return (u16)((__builtin_bit_cast(unsigned int, f) + 0x8000u) >> 16);
}
// pack bf16(a) into low16, bf16(b) into high16 — 2 adds + 1 v_perm
__device__ __forceinline__ u32 pk2(float a, float b) {
  u32 ua = __builtin_bit_cast(u32, a) + 0x8000u;
  u32 ub = __builtin_bit_cast(u32, b) + 0x8000u;
  return __builtin_amdgcn_perm(ub, ua, 0x07060302u);
}

// XOR-swizzled index into a [64][256] u16 LDS tile (16B-granular swizzle).
// Row stride 512B would otherwise put stride-1-row column reads 32-way on the
// same bank; XOR of (row&7) into the 16B-slot index spreads them (2-way = free).
__device__ __forceinline__ int swz(int row, int col) {
  return (row << 8) + (col ^ ((row & 7) << 3));
}

// ---- prep: weight pre-pack (blocks 0..127) + K/V precompute (all blocks) ----
// w1p slot = (jblk*8 + kblk)*64 + lane   (jblk: 32, kblk: 8)
// w2p slot = (oblk*16 + kblk)*64 + lane  (oblk: 16, kblk: 16)
__global__ __launch_bounds__(256) void prep_kernel(
    const float* __restrict__ ff1w, const float* __restrict__ ff2w,
    u16* __restrict__ w1p, u16* __restrict__ w2p,
    const float* __restrict__ tokens, const float* __restrict__ kw,
    const float* __restrict__ vw, const float* __restrict__ gate,
    float* __restrict__ ws_kv) {
  int bid = blockIdx.x;
  if (bid < 128) {
    int idx = bid * 256 + threadIdx.x;  // 0..32767
    int lane = idx & 63;
    int m = lane & 15, q = lane >> 4;
    if (idx < 16384) {
      int kblk = (idx >> 6) & 7;
      int jblk = idx >> 9;
      const float* src = ff1w + (size_t)(jblk * 16 + m) * QC + kblk * 32 + q * 8;
      u16* dst = w1p + (size_t)idx * 8;
#pragma unroll
      for (int i = 0; i < 8; i++) dst[i] = f2b(src[i]);
    } else {
      int s2 = idx - 16384;
      int kblk = (s2 >> 6) & 15;
      int oblk = s2 >> 10;
      const float* src = ff2w + (size_t)(oblk * 16 + m) * KVC + kblk * 32 + q * 8;
      u16* dst = w2p + (size_t)s2 * 8;
#pragma unroll
      for (int i = 0; i < 8; i++) dst[i] = f2b(src[i]);
    }
  }
  // ---- K/V (only does work when tanh(gate) != 0) ----
  float tg = tanhf(gate[0]);
  if (tg == 0.0f) return;
  {
    int b = bid >> 8;
    int n = bid & 255;
    __shared__ float tok[KVC];
    for (int c = threadIdx.x; c < KVC; c += 256)
      tok[c] = tokens[((size_t)(b * NT + n)) * KVC + c];
    __syncthreads();
    int tid = threadIdx.x;
    int t = tid & 127;
    const float* w = (tid < 128) ? kw : vw;
    const float* wr = w + (size_t)t * KVC;
    float acc = 0.f;
    for (int c = 0; c < KVC; c += 4) {
      float4 wv = *(const float4*)(wr + c);
      acc += tok[c] * wv.x + tok[c + 1] * wv.y + tok[c + 2] * wv.z + tok[c + 3] * wv.w;
    }
    int h = t >> 5, d = t & 31;
    float* dst = ws_kv + ((tid < 128) ? 0 : NB * NH * NT * DH);
    dst[(((b * NH + h) * NT) + n) * DH + d] = acc;
  }
}

// ---- fused: [attention+proj+gated residual if gate!=0] + MFMA FFN + residual ----
// 512 threads (8 waves). Register budget pinned at 128 VGPR via
// amdgpu_waves_per_eu(4): round-1's __launch_bounds__(512,4) was interpreted
// as a 64-reg budget and spilled accumulators (WRITE_SIZE 65->182 MB).
// LDS 64 KB -> 2 blocks/CU = 16 waves/CU; grid 1024 = 2 clean rounds.
// j chunked 2x256; per chunk: GEMM1 (m=4 x n=2, K=256) -> SiLU -> GEMM2 partial
// (m=4 x n=2, K=256). Rolling depth-4 B-fragment prefetch; GEMM2 preloads
// issued before the barrier so L2 latency hides under the barrier wait.
__global__ __launch_bounds__(512) __attribute__((amdgpu_waves_per_eu(4)))
void fused_kernel(
    const float* __restrict__ feat, const float* __restrict__ qw,
    const float* __restrict__ qb, const float* __restrict__ projw,
    const float* __restrict__ projb, const float* __restrict__ ff1b,
    const float* __restrict__ ff2b, const u16* __restrict__ w1p,
    const u16* __restrict__ w2p, const float* __restrict__ gate,
    const float* __restrict__ ws_kv, float* __restrict__ out) {
  __shared__ u16 sX[64 * 256];  // feat/out1 tile [s][c], swizzled, 32 KB
  __shared__ u16 sH[64 * 256];  // hidden chunk / attn buf [s][j], swizzled, 32 KB

  int b = blockIdx.x >> 8;
  int s0 = (blockIdx.x & 255) * TSP;
  int tid = threadIdx.x;
  int w = tid >> 6;     // wave 0..7
  int lane = tid & 63;
  int lm = lane & 15, lq = lane >> 4;

  // ---- stage feat tile transposed: global [c][s] fp32 -> LDS [s][c] bf16 ----
  {
    const float* fb = feat + (((size_t)b * QC) << 14) + s0;
    int cq = (tid >> 4) * 4;   // c quad base 0..124
    int sq = (tid & 15) * 4;   // s quad
#pragma unroll
    for (int it = 0; it < 2; ++it) {
      int c = it * 128 + cq;
      float4 r0 = *(const float4*)(fb + ((size_t)(c + 0) << 14) + sq);
      float4 r1 = *(const float4*)(fb + ((size_t)(c + 1) << 14) + sq);
      float4 r2 = *(const float4*)(fb + ((size_t)(c + 2) << 14) + sq);
      float4 r3 = *(const float4*)(fb + ((size_t)(c + 3) << 14) + sq);
      uint2 d0, d1, d2, d3;
      d0.x = pk2(r0.x, r1.x); d0.y = pk2(r2.x, r3.x);
      d1.x = pk2(r0.y, r1.y); d1.y = pk2(r2.y, r3.y);
      d2.x = pk2(r0.z, r1.z); d2.y = pk2(r2.z, r3.z);
      d3.x = pk2(r0.w, r1.w); d3.y = pk2(r2.w, r3.w);
      *(uint2*)&sX[swz(sq + 0, c)] = d0;
      *(uint2*)&sX[swz(sq + 1, c)] = d1;
      *(uint2*)&sX[swz(sq + 2, c)] = d2;
      *(uint2*)&sX[swz(sq + 3, c)] = d3;
    }
  }
  float tg = tanhf(gate[0]);
  __syncthreads();

  if (tg != 0.0f) {
    if (w < 4) {
      // ---- Q for head w, spatial position `lane` ----
      float qreg[DH];
#pragma unroll
      for (int d = 0; d < DH; d++) {
        int o = w * DH + d;
        float a = qb[o];
        const float* qr = qw + (size_t)o * QC;
        for (int c = 0; c < QC; c += 4) {
          float4 wv = *(const float4*)(qr + c);
          a += b2f(sX[swz(lane, c + 0)]) * wv.x;
          a += b2f(sX[swz(lane, c + 1)]) * wv.y;
          a += b2f(sX[swz(lane, c + 2)]) * wv.z;
          a += b2f(sX[swz(lane, c + 3)]) * wv.w;
        }
        qreg[d] = a;
      }
      // ---- online-softmax attention over NT tokens ----
      const float* Kp = ws_kv + (size_t)(b * NH + w) * NT * DH;
      const float* Vp = Kp + NB * NH * NT * DH;
      float m_ = -1e30f, l_ = 0.f;
      float oacc[DH];
#pragma unroll
      for (int d = 0; d < DH; d++) oacc[d] = 0.f;
      const float scale = 0.17677669529663687f;  // 1/sqrt(32)
      for (int n = 0; n < NT; n++) {
        const float* kr = Kp + n * DH;
        float s = 0.f;
#pragma unroll
        for (int d = 0; d < DH; d++) s += qreg[d] * kr[d];
        s *= scale;
        float nm = fmaxf(m_, s);
        float p = __expf(s - nm);
        float al = __expf(m_ - nm);
        const float* vr = Vp + n * DH;
        l_ = l_ * al + p;
#pragma unroll
        for (int d = 0; d < DH; d++) oacc[d] = oacc[d] * al + p * vr[d];
        m_ = nm;
      }
      float inv = 1.0f / l_;
#pragma unroll
      for (int d = 0; d < DH; d++)
        sH[swz(lane, w * DH + d)] = f2b(oacc[d] * inv);  // sattn [s][t=128]
    }
    __syncthreads();
    // ---- proj + gated residual into sX (wave w owns channels w*32..+32) ----
    for (int ci = 0; ci < 32; ci++) {
      int c = w * 32 + ci;
      float a = projb[c];
      const float* pr = projw + (size_t)c * TC;
      for (int t = 0; t < TC; t += 4) {
        float4 wv = *(const float4*)(pr + t);
        a += b2f(sH[swz(lane, t + 0)]) * wv.x;
        a += b2f(sH[swz(lane, t + 1)]) * wv.y;
        a += b2f(sH[swz(lane, t + 2)]) * wv.z;
        a += b2f(sH[swz(lane, t + 3)]) * wv.w;
      }
      float o1 = b2f(sX[swz(lane, c)]) + tg * a;
      sX[swz(lane, c)] = f2b(o1);
    }
    __syncthreads();
  }

  // ---- MFMA FFN; biases folded into accumulator init ----
  f32x4 acc2[2][4];  // [t = o-block][m = s-block]
#pragma unroll
  for (int t = 0; t < 2; t++) {
    float b2v = ff2b[(w * 2 + t) * 16 + lm];
    f32x4 iv = {b2v, b2v, b2v, b2v};
#pragma unroll
    for (int m = 0; m < 4; m++) acc2[t][m] = iv;
  }

#pragma unroll 1
  for (int ch = 0; ch < 2; ++ch) {
    // ---- GEMM1: wave handles j-blocks {ch*16 + 2w, +1}, K = 256 ----
    f32x4 acc1[2][4];
#pragma unroll
    for (int t = 0; t < 2; t++) {
      float b1v = ff1b[ch * 256 + (w * 2 + t) * 16 + lm];
      f32x4 iv = {b1v, b1v, b1v, b1v};
#pragma unroll
      for (int m = 0; m < 4; m++) acc1[t][m] = iv;
    }
    {
      int jb0 = ch * 16 + w * 2;
      const u16* p0 = w1p + (((size_t)jb0 * 8) * 64 + lane) * 8;
      const u16* p1 = p0 + 4096;  // next j-block (8 kblks * 512)
      // depth-4 rolling B pipeline (stride per k-step: 512 u16)
      bf16x8 q0[4], q1[4];
#pragma unroll
      for (int k = 0; k < 4; k++) {
        q0[k] = *(const bf16x8*)(p0 + (size_t)k * 512);
        q1[k] = *(const bf16x8*)(p1 + (size_t)k * 512);
      }
#pragma unroll
      for (int k = 0; k < 8; ++k) {
        bf16x8 u0 = q0[k & 3], u1 = q1[k & 3];
        if (k < 4) {
          q0[k & 3] = *(const bf16x8*)(p0 + (size_t)(k + 4) * 512);
          q1[k & 3] = *(const bf16x8*)(p1 + (size_t)(k + 4) * 512);
        }
        int col = k * 32 + lq * 8;
#pragma unroll
        for (int m = 0; m < 4; m++) {
          bf16x8 a = *(const bf16x8*)&sX[swz(m * 16 + lm, col)];
          acc1[0][m] = __builtin_amdgcn_mfma_f32_16x16x32_bf16(a, u0, acc1[0][m], 0, 0, 0);
          acc1[1][m] = __builtin_amdgcn_mfma_f32_16x16x32_bf16(a, u1, acc1[1][m], 0, 0, 0);
        }
      }
    }
    __syncthreads();  // previous chunk's GEMM2 reads of sH complete
    // SiLU (bias already in acc) -> sH[s][j_local]
#pragma unroll
    for (int t = 0; t < 2; t++) {
      int jl = (w * 2 + t) * 16 + lm;
#pragma unroll
      for (int m = 0; m < 4; m++) {
        int sb = m * 16 + lq * 4;
        f32x4 v = acc1[t][m];
#pragma unroll
        for (int r = 0; r < 4; r++) {
          float x = v[r];
          float sl = x * __builtin_amdgcn_rcpf(1.f + __expf(-x));
          sH[swz(sb + r, jl)] = f2b_fast(sl);
        }
      }
    }
    // GEMM2 B preload issued BEFORE the barrier: latency hides under the wait
    const u16* qp0 = w2p + (((size_t)((w * 2) * 16 + ch * 8)) * 64 + lane) * 8;
    const u16* qp1 = qp0 + 8192;  // next o-block (16 kblks * 512)
    bf16x8 r0[4], r1[4];
#pragma unroll
    for (int k = 0; k < 4; k++) {
      r0[k] = *(const bf16x8*)(qp0 + (size_t)k * 512);
      r1[k] = *(const bf16x8*)(qp1 + (size_t)k * 512);
    }
    __syncthreads();  // sH ready
    // ---- GEMM2 partial: K = this 256-j chunk; wave handles o-blocks {2w, 2w+1} ----
#pragma unroll
    for (int k = 0; k < 8; ++k) {
      bf16x8 u0 = r0[k & 3], u1 = r1[k & 3];
      if (k < 4) {
        r0[k & 3] = *(const bf16x8*)(qp0 + (size_t)(k + 4) * 512);
        r1[k & 3] = *(const bf16x8*)(qp1 + (size_t)(k + 4) * 512);
      }
      int col = k * 32 + lq * 8;
#pragma unroll
      for (int m = 0; m < 4; m++) {
        bf16x8 a = *(const bf16x8*)&sH[swz(m * 16 + lm, col)];
        acc2[0][m] = __builtin_amdgcn_mfma_f32_16x16x32_bf16(a, u0, acc2[0][m], 0, 0, 0);
        acc2[1][m] = __builtin_amdgcn_mfma_f32_16x16x32_bf16(a, u1, acc2[1][m], 0, 0, 0);
      }
    }
  }

  // ---- epilogue: out[c][s] = out1 + ff (bias already in acc2) ----
#pragma unroll
  for (int t = 0; t < 2; t++) {
    int c = (w * 2 + t) * 16 + lm;
#pragma unroll
    for (int m = 0; m < 4; m++) {
      int sb = m * 16 + lq * 4;
      f32x4 v = acc2[t][m];
      float4 ov;
      ov.x = v[0] + b2f(sX[swz(sb + 0, c)]);
      ov.y = v[1] + b2f(sX[swz(sb + 1, c)]);
      ov.z = v[2] + b2f(sX[swz(sb + 2, c)]);
      ov.w = v[3] + b2f(sX[swz(sb + 3, c)]);
      *(float4*)(out + (((size_t)(b * QC + c)) << 14) + s0 + sb) = ov;
    }
  }
}

extern "C" void kernel_launch(void* const* d_in, const int* in_sizes, int n_in,
                              void* d_out, int out_size, void* d_ws, size_t ws_size,
                              hipStream_t stream) {
  const float* feat   = (const float*)d_in[0];
  const float* tokens = (const float*)d_in[1];
  const float* qw     = (const float*)d_in[2];
  const float* qb     = (const float*)d_in[3];
  const float* kw     = (const float*)d_in[4];
  const float* vw     = (const float*)d_in[5];
  const float* projw  = (const float*)d_in[6];
  const float* projb  = (const float*)d_in[7];
  const float* ff1w   = (const float*)d_in[8];
  const float* ff1b   = (const float*)d_in[9];
  const float* ff2w   = (const float*)d_in[10];
  const float* ff2b   = (const float*)d_in[11];
  const float* gate   = (const float*)d_in[12];
  float* out = (float*)d_out;

  u16* w1p = (u16*)d_ws;                               // 256 KB
  u16* w2p = w1p + 131072;                             // 256 KB
  float* ws_kv = (float*)((char*)d_ws + 524288);       // 1 MB (K then V)

  prep_kernel<<<dim3(NB * NT), dim3(256), 0, stream>>>(
      ff1w, ff2w, w1p, w2p, tokens, kw, vw, gate, ws_kv);
  fused_kernel<<<dim3(NB * (SD / TSP)), dim3(512), 0, stream>>>(
      feat, qw, qb, projw, projb, ff1b, ff2b, w1p, w2p, gate, ws_kv, out);
}

// Round 3
// 208.735 us; speedup vs baseline: 1.0042x; 1.0042x over previous
//
#include <hip/hip_runtime.h>

// Problem constants (CrossAttention_73856257622246)
#define NB 4      // batch
#define QC 256    // query channels
#define SD 16384  // Z*H*W spatial per batch
#define NT 256    // tokens
#define KVC 512   // token channels
#define TC 128    // TOKEN_CH
#define NH 4      // heads
#define DH 32     // head dim
#define TSP 64    // spatial tile per block

typedef unsigned short u16;
typedef unsigned int u32;
typedef __attribute__((ext_vector_type(8))) short bf16x8;  // MFMA A/B frag (4 VGPR)
typedef __attribute__((ext_vector_type(4))) float f32x4;   // MFMA C/D frag

__device__ __forceinline__ float b2f(u16 u) {
  unsigned int v = ((unsigned int)u) << 16;
  return __builtin_bit_cast(float, v);
}
__device__ __forceinline__ u16 f2b(float f) {  // RNE (used in cold paths / packing)
  unsigned int x = __builtin_bit_cast(unsigned int, f);
  unsigned int r = (x + 0x7fffu + ((x >> 16) & 1u)) >> 16;
  return (u16)r;
}
__device__ __forceinline__ u16 f2b_fast(float f) {  // round-half-up, 2 VALU
  return (u16)((__builtin_bit_cast(unsigned int, f) + 0x8000u) >> 16);
}
// pack bf16(a) into low16, bf16(b) into high16 — 2 adds + 1 v_perm
__device__ __forceinline__ u32 pk2(float a, float b) {
  u32 ua = __builtin_bit_cast(u32, a) + 0x8000u;
  u32 ub = __builtin_bit_cast(u32, b) + 0x8000u;
  return __builtin_amdgcn_perm(ub, ua, 0x07060302u);
}

// XOR-swizzled index into a [64][256] u16 LDS tile (16B-granular swizzle).
__device__ __forceinline__ int swz(int row, int col) {
  return (row << 8) + (col ^ ((row & 7) << 3));
}

// ---- prep: weight pre-pack (blocks 0..127) + K/V precompute (all blocks) ----
// w1p slot = (jblk*8 + kblk)*64 + lane   (jblk: 32, kblk: 8)
// w2p slot = (oblk*16 + kblk)*64 + lane  (oblk: 16, kblk: 16)
__global__ __launch_bounds__(256) void prep_kernel(
    const float* __restrict__ ff1w, const float* __restrict__ ff2w,
    u16* __restrict__ w1p, u16* __restrict__ w2p,
    const float* __restrict__ tokens, const float* __restrict__ kw,
    const float* __restrict__ vw, const float* __restrict__ gate,
    float* __restrict__ ws_kv) {
  int bid = blockIdx.x;
  if (bid < 128) {
    int idx = bid * 256 + threadIdx.x;  // 0..32767
    int lane = idx & 63;
    int m = lane & 15, q = lane >> 4;
    if (idx < 16384) {
      int kblk = (idx >> 6) & 7;
      int jblk = idx >> 9;
      const float* src = ff1w + (size_t)(jblk * 16 + m) * QC + kblk * 32 + q * 8;
      u16* dst = w1p + (size_t)idx * 8;
#pragma unroll
      for (int i = 0; i < 8; i++) dst[i] = f2b(src[i]);
    } else {
      int s2 = idx - 16384;
      int kblk = (s2 >> 6) & 15;
      int oblk = s2 >> 10;
      const float* src = ff2w + (size_t)(oblk * 16 + m) * KVC + kblk * 32 + q * 8;
      u16* dst = w2p + (size_t)s2 * 8;
#pragma unroll
      for (int i = 0; i < 8; i++) dst[i] = f2b(src[i]);
    }
  }
  // ---- K/V (only does work when tanh(gate) != 0) ----
  float tg = tanhf(gate[0]);
  if (tg == 0.0f) return;
  {
    int b = bid >> 8;
    int n = bid & 255;
    __shared__ float tok[KVC];
    for (int c = threadIdx.x; c < KVC; c += 256)
      tok[c] = tokens[((size_t)(b * NT + n)) * KVC + c];
    __syncthreads();
    int tid = threadIdx.x;
    int t = tid & 127;
    const float* w = (tid < 128) ? kw : vw;
    const float* wr = w + (size_t)t * KVC;
    float acc = 0.f;
    for (int c = 0; c < KVC; c += 4) {
      float4 wv = *(const float4*)(wr + c);
      acc += tok[c] * wv.x + tok[c + 1] * wv.y + tok[c + 2] * wv.z + tok[c + 3] * wv.w;
    }
    int h = t >> 5, d = t & 31;
    float* dst = ws_kv + ((tid < 128) ? 0 : NB * NH * NT * DH);
    dst[(((b * NH + h) * NT) + n) * DH + d] = acc;
  }
}

// ---- fused: [attention+proj+gated residual if gate!=0] + MFMA FFN + residual ----
// 512 threads (8 waves), __launch_bounds__(512,4) = 4 waves/EU = 128-reg total
// budget (arch + AGPR, unified file). Round-1/2 spilled because demand was
// ~150 (depth-4 prefetch); this version uses round-0's proven depth-2 rolling
// prefetch so demand ~= 64 AGPR (acc) + ~50 arch < 128 -> no scratch.
// LDS 64 KB -> 2 blocks/CU = 16 waves/CU; grid 1024 = 2 clean rounds.
// j chunked 2x256; per chunk: GEMM1 (m=4 x n=2, K=256) -> SiLU -> GEMM2 partial
// (m=4 x n=2, K=256). GEMM2's first 2 k-step weights are loaded before the sH
// barrier so their L2 latency hides under the wait.
__global__ __launch_bounds__(512, 4) void fused_kernel(
    const float* __restrict__ feat, const float* __restrict__ qw,
    const float* __restrict__ qb, const float* __restrict__ projw,
    const float* __restrict__ projb, const float* __restrict__ ff1b,
    const float* __restrict__ ff2b, const u16* __restrict__ w1p,
    const u16* __restrict__ w2p, const float* __restrict__ gate,
    const float* __restrict__ ws_kv, float* __restrict__ out) {
  __shared__ u16 sX[64 * 256];  // feat/out1 tile [s][c], swizzled, 32 KB
  __shared__ u16 sH[64 * 256];  // hidden chunk / attn buf [s][j], swizzled, 32 KB

  int b = blockIdx.x >> 8;
  int s0 = (blockIdx.x & 255) * TSP;
  int tid = threadIdx.x;
  int w = tid >> 6;     // wave 0..7
  int lane = tid & 63;
  int lm = lane & 15, lq = lane >> 4;

  // ---- stage feat tile transposed: global [c][s] fp32 -> LDS [s][c] bf16 ----
  {
    const float* fb = feat + (((size_t)b * QC) << 14) + s0;
    int cq = (tid >> 4) * 4;   // c quad base 0..124
    int sq = (tid & 15) * 4;   // s quad
#pragma unroll
    for (int it = 0; it < 2; ++it) {
      int c = it * 128 + cq;
      float4 r0 = *(const float4*)(fb + ((size_t)(c + 0) << 14) + sq);
      float4 r1 = *(const float4*)(fb + ((size_t)(c + 1) << 14) + sq);
      float4 r2 = *(const float4*)(fb + ((size_t)(c + 2) << 14) + sq);
      float4 r3 = *(const float4*)(fb + ((size_t)(c + 3) << 14) + sq);
      uint2 d0, d1, d2, d3;
      d0.x = pk2(r0.x, r1.x); d0.y = pk2(r2.x, r3.x);
      d1.x = pk2(r0.y, r1.y); d1.y = pk2(r2.y, r3.y);
      d2.x = pk2(r0.z, r1.z); d2.y = pk2(r2.z, r3.z);
      d3.x = pk2(r0.w, r1.w); d3.y = pk2(r2.w, r3.w);
      *(uint2*)&sX[swz(sq + 0, c)] = d0;
      *(uint2*)&sX[swz(sq + 1, c)] = d1;
      *(uint2*)&sX[swz(sq + 2, c)] = d2;
      *(uint2*)&sX[swz(sq + 3, c)] = d3;
    }
  }
  float tg = tanhf(gate[0]);
  __syncthreads();

  if (tg != 0.0f) {
    if (w < 4) {
      // ---- Q for head w, spatial position `lane` ----
      float qreg[DH];
#pragma unroll
      for (int d = 0; d < DH; d++) {
        int o = w * DH + d;
        float a = qb[o];
        const float* qr = qw + (size_t)o * QC;
        for (int c = 0; c < QC; c += 4) {
          float4 wv = *(const float4*)(qr + c);
          a += b2f(sX[swz(lane, c + 0)]) * wv.x;
          a += b2f(sX[swz(lane, c + 1)]) * wv.y;
          a += b2f(sX[swz(lane, c + 2)]) * wv.z;
          a += b2f(sX[swz(lane, c + 3)]) * wv.w;
        }
        qreg[d] = a;
      }
      // ---- online-softmax attention over NT tokens ----
      const float* Kp = ws_kv + (size_t)(b * NH + w) * NT * DH;
      const float* Vp = Kp + NB * NH * NT * DH;
      float m_ = -1e30f, l_ = 0.f;
      float oacc[DH];
#pragma unroll
      for (int d = 0; d < DH; d++) oacc[d] = 0.f;
      const float scale = 0.17677669529663687f;  // 1/sqrt(32)
      for (int n = 0; n < NT; n++) {
        const float* kr = Kp + n * DH;
        float s = 0.f;
#pragma unroll
        for (int d = 0; d < DH; d++) s += qreg[d] * kr[d];
        s *= scale;
        float nm = fmaxf(m_, s);
        float p = __expf(s - nm);
        float al = __expf(m_ - nm);
        const float* vr = Vp + n * DH;
        l_ = l_ * al + p;
#pragma unroll
        for (int d = 0; d < DH; d++) oacc[d] = oacc[d] * al + p * vr[d];
        m_ = nm;
      }
      float inv = 1.0f / l_;
#pragma unroll
      for (int d = 0; d < DH; d++)
        sH[swz(lane, w * DH + d)] = f2b(oacc[d] * inv);  // sattn [s][t=128]
    }
    __syncthreads();
    // ---- proj + gated residual into sX (wave w owns channels w*32..+32) ----
    for (int ci = 0; ci < 32; ci++) {
      int c = w * 32 + ci;
      float a = projb[c];
      const float* pr = projw + (size_t)c * TC;
      for (int t = 0; t < TC; t += 4) {
        float4 wv = *(const float4*)(pr + t);
        a += b2f(sH[swz(lane, t + 0)]) * wv.x;
        a += b2f(sH[swz(lane, t + 1)]) * wv.y;
        a += b2f(sH[swz(lane, t + 2)]) * wv.z;
        a += b2f(sH[swz(lane, t + 3)]) * wv.w;
      }
      float o1 = b2f(sX[swz(lane, c)]) + tg * a;
      sX[swz(lane, c)] = f2b(o1);
    }
    __syncthreads();
  }

  // ---- MFMA FFN; biases folded into accumulator init ----
  f32x4 acc2[2][4];  // [t = o-block][m = s-block]
#pragma unroll
  for (int t = 0; t < 2; t++) {
    float b2v = ff2b[(w * 2 + t) * 16 + lm];
    f32x4 iv = {b2v, b2v, b2v, b2v};
#pragma unroll
    for (int m = 0; m < 4; m++) acc2[t][m] = iv;
  }

#pragma unroll 1
  for (int ch = 0; ch < 2; ++ch) {
    // ---- GEMM1: wave handles j-blocks {ch*16 + 2w, +1}, K = 256 ----
    f32x4 acc1[2][4];
#pragma unroll
    for (int t = 0; t < 2; t++) {
      float b1v = ff1b[ch * 256 + (w * 2 + t) * 16 + lm];
      f32x4 iv = {b1v, b1v, b1v, b1v};
#pragma unroll
      for (int m = 0; m < 4; m++) acc1[t][m] = iv;
    }
    {
      int jb0 = ch * 16 + w * 2;
      const u16* p0 = w1p + (((size_t)jb0 * 8) * 64 + lane) * 8;
      const u16* p1 = p0 + 4096;  // next j-block (8 kblks * 512)
      // depth-2 rolling B pipeline (round-0 proven; stride per k-step 512 u16)
      bf16x8 c0 = *(const bf16x8*)(p0);
      bf16x8 c1 = *(const bf16x8*)(p1);
      bf16x8 n0 = *(const bf16x8*)(p0 + 512);
      bf16x8 n1 = *(const bf16x8*)(p1 + 512);
#pragma unroll
      for (int k = 0; k < 8; ++k) {
        bf16x8 f0, f1;
        if (k < 6) {
          f0 = *(const bf16x8*)(p0 + (size_t)(k + 2) * 512);
          f1 = *(const bf16x8*)(p1 + (size_t)(k + 2) * 512);
        }
        int col = k * 32 + lq * 8;
#pragma unroll
        for (int m = 0; m < 4; m++) {
          bf16x8 a = *(const bf16x8*)&sX[swz(m * 16 + lm, col)];
          acc1[0][m] = __builtin_amdgcn_mfma_f32_16x16x32_bf16(a, c0, acc1[0][m], 0, 0, 0);
          acc1[1][m] = __builtin_amdgcn_mfma_f32_16x16x32_bf16(a, c1, acc1[1][m], 0, 0, 0);
        }
        c0 = n0; c1 = n1;
        if (k < 6) { n0 = f0; n1 = f1; }
      }
    }
    __syncthreads();  // previous chunk's GEMM2 reads of sH complete
    // SiLU (bias already in acc) -> sH[s][j_local]
#pragma unroll
    for (int t = 0; t < 2; t++) {
      int jl = (w * 2 + t) * 16 + lm;
#pragma unroll
      for (int m = 0; m < 4; m++) {
        int sb = m * 16 + lq * 4;
        f32x4 v = acc1[t][m];
#pragma unroll
        for (int r = 0; r < 4; r++) {
          float x = v[r];
          float sl = x * __builtin_amdgcn_rcpf(1.f + __expf(-x));
          sH[swz(sb + r, jl)] = f2b_fast(sl);
        }
      }
    }
    // GEMM2 first 2 k-step weights loaded BEFORE the barrier: latency hides
    const u16* qp0 = w2p + (((size_t)((w * 2) * 16 + ch * 8)) * 64 + lane) * 8;
    const u16* qp1 = qp0 + 8192;  // next o-block (16 kblks * 512)
    bf16x8 d0 = *(const bf16x8*)(qp0);
    bf16x8 d1 = *(const bf16x8*)(qp1);
    bf16x8 e0 = *(const bf16x8*)(qp0 + 512);
    bf16x8 e1 = *(const bf16x8*)(qp1 + 512);
    __syncthreads();  // sH ready
    // ---- GEMM2 partial: K = this 256-j chunk; wave handles o-blocks {2w, 2w+1} ----
#pragma unroll
    for (int k = 0; k < 8; ++k) {
      bf16x8 f0, f1;
      if (k < 6) {
        f0 = *(const bf16x8*)(qp0 + (size_t)(k + 2) * 512);
        f1 = *(const bf16x8*)(qp1 + (size_t)(k + 2) * 512);
      }
      int col = k * 32 + lq * 8;
#pragma unroll
      for (int m = 0; m < 4; m++) {
        bf16x8 a = *(const bf16x8*)&sH[swz(m * 16 + lm, col)];
        acc2[0][m] = __builtin_amdgcn_mfma_f32_16x16x32_bf16(a, d0, acc2[0][m], 0, 0, 0);
        acc2[1][m] = __builtin_amdgcn_mfma_f32_16x16x32_bf16(a, d1, acc2[1][m], 0, 0, 0);
      }
      d0 = e0; d1 = e1;
      if (k < 6) { e0 = f0; e1 = f1; }
    }
  }

  // ---- epilogue: out[c][s] = out1 + ff (bias already in acc2) ----
#pragma unroll
  for (int t = 0; t < 2; t++) {
    int c = (w * 2 + t) * 16 + lm;
#pragma unroll
    for (int m = 0; m < 4; m++) {
      int sb = m * 16 + lq * 4;
      f32x4 v = acc2[t][m];
      float4 ov;
      ov.x = v[0] + b2f(sX[swz(sb + 0, c)]);
      ov.y = v[1] + b2f(sX[swz(sb + 1, c)]);
      ov.z = v[2] + b2f(sX[swz(sb + 2, c)]);
      ov.w = v[3] + b2f(sX[swz(sb + 3, c)]);
      *(float4*)(out + (((size_t)(b * QC + c)) << 14) + s0 + sb) = ov;
    }
  }
}

extern "C" void kernel_launch(void* const* d_in, const int* in_sizes, int n_in,
                              void* d_out, int out_size, void* d_ws, size_t ws_size,
                              hipStream_t stream) {
  const float* feat   = (const float*)d_in[0];
  const float* tokens = (const float*)d_in[1];
  const float* qw     = (const float*)d_in[2];
  const float* qb     = (const float*)d_in[3];
  const float* kw     = (const float*)d_in[4];
  const float* vw     = (const float*)d_in[5];
  const float* projw  = (const float*)d_in[6];
  const float* projb  = (const float*)d_in[7];
  const float* ff1w   = (const float*)d_in[8];
  const float* ff1b   = (const float*)d_in[9];
  const float* ff2w   = (const float*)d_in[10];
  const float* ff2b   = (const float*)d_in[11];
  const float* gate   = (const float*)d_in[12];
  float* out = (float*)d_out;

  u16* w1p = (u16*)d_ws;                               // 256 KB
  u16* w2p = w1p + 131072;                             // 256 KB
  float* ws_kv = (float*)((char*)d_ws + 524288);       // 1 MB (K then V)

  prep_kernel<<<dim3(NB * NT), dim3(256), 0, stream>>>(
      ff1w, ff2w, w1p, w2p, tokens, kw, vw, gate, ws_kv);
  fused_kernel<<<dim3(NB * (SD / TSP)), dim3(512), 0, stream>>>(
      feat, qw, qb, projw, projb, ff1b, ff2b, w1p, w2p, gate, ws_kv, out);
}

// Round 4
// 171.427 us; speedup vs baseline: 1.2227x; 1.2176x over previous
//
#include <hip/hip_runtime.h>

// Problem constants (CrossAttention_73856257622246)
#define NB 4      // batch
#define QC 256    // query channels
#define SD 16384  // Z*H*W spatial per batch
#define NT 256    // tokens
#define KVC 512   // token channels
#define TC 128    // TOKEN_CH
#define NH 4      // heads
#define DH 32     // head dim
#define TSP 64    // spatial tile per block

typedef unsigned short u16;
typedef unsigned int u32;
typedef __attribute__((ext_vector_type(8))) short bf16x8;  // MFMA A/B frag (4 VGPR)
typedef __attribute__((ext_vector_type(4))) float f32x4;   // MFMA C/D frag

__device__ __forceinline__ float b2f(u16 u) {
  unsigned int v = ((unsigned int)u) << 16;
  return __builtin_bit_cast(float, v);
}
__device__ __forceinline__ u16 f2b(float f) {  // RNE (used in cold paths / packing)
  unsigned int x = __builtin_bit_cast(unsigned int, f);
  unsigned int r = (x + 0x7fffu + ((x >> 16) & 1u)) >> 16;
  return (u16)r;
}
__device__ __forceinline__ u16 f2b_fast(float f) {  // round-half-up, 2 VALU
  return (u16)((__builtin_bit_cast(unsigned int, f) + 0x8000u) >> 16);
}
// pack bf16(a) into low16, bf16(b) into high16 — 2 adds + 1 v_perm
__device__ __forceinline__ u32 pk2(float a, float b) {
  u32 ua = __builtin_bit_cast(u32, a) + 0x8000u;
  u32 ub = __builtin_bit_cast(u32, b) + 0x8000u;
  return __builtin_amdgcn_perm(ub, ua, 0x07060302u);
}

// XOR-swizzled index into a [64][256] u16 LDS tile (16B-granular swizzle).
__device__ __forceinline__ int swz(int row, int col) {
  return (row << 8) + (col ^ ((row & 7) << 3));
}
// Same for a [64][128] u16 half-tile (row stride 256 B).
__device__ __forceinline__ int swzH(int row, int col) {
  return (row << 7) + (col ^ ((row & 7) << 3));
}

// ---- prep: weight pre-pack (blocks 0..127) + K/V precompute (all blocks) ----
// w1p slot = (jblk*8 + kblk)*64 + lane   (jblk: 32, kblk: 8)
// w2p slot = (oblk*16 + kblk)*64 + lane  (oblk: 16, kblk: 16)
__global__ __launch_bounds__(256) void prep_kernel(
    const float* __restrict__ ff1w, const float* __restrict__ ff2w,
    u16* __restrict__ w1p, u16* __restrict__ w2p,
    const float* __restrict__ tokens, const float* __restrict__ kw,
    const float* __restrict__ vw, const float* __restrict__ gate,
    float* __restrict__ ws_kv) {
  int bid = blockIdx.x;
  if (bid < 128) {
    int idx = bid * 256 + threadIdx.x;  // 0..32767
    int lane = idx & 63;
    int m = lane & 15, q = lane >> 4;
    if (idx < 16384) {
      int kblk = (idx >> 6) & 7;
      int jblk = idx >> 9;
      const float* src = ff1w + (size_t)(jblk * 16 + m) * QC + kblk * 32 + q * 8;
      u16* dst = w1p + (size_t)idx * 8;
#pragma unroll
      for (int i = 0; i < 8; i++) dst[i] = f2b(src[i]);
    } else {
      int s2 = idx - 16384;
      int kblk = (s2 >> 6) & 15;
      int oblk = s2 >> 10;
      const float* src = ff2w + (size_t)(oblk * 16 + m) * KVC + kblk * 32 + q * 8;
      u16* dst = w2p + (size_t)s2 * 8;
#pragma unroll
      for (int i = 0; i < 8; i++) dst[i] = f2b(src[i]);
    }
  }
  // ---- K/V (only does work when tanh(gate) != 0) ----
  float tg = tanhf(gate[0]);
  if (tg == 0.0f) return;
  {
    int b = bid >> 8;
    int n = bid & 255;
    __shared__ float tok[KVC];
    for (int c = threadIdx.x; c < KVC; c += 256)
      tok[c] = tokens[((size_t)(b * NT + n)) * KVC + c];
    __syncthreads();
    int tid = threadIdx.x;
    int t = tid & 127;
    const float* w = (tid < 128) ? kw : vw;
    const float* wr = w + (size_t)t * KVC;
    float acc = 0.f;
    for (int c = 0; c < KVC; c += 4) {
      float4 wv = *(const float4*)(wr + c);
      acc += tok[c] * wv.x + tok[c + 1] * wv.y + tok[c + 2] * wv.z + tok[c + 3] * wv.w;
    }
    int h = t >> 5, d = t & 31;
    float* dst = ws_kv + ((tid < 128) ? 0 : NB * NH * NT * DH);
    dst[(((b * NH + h) * NT) + n) * DH + d] = acc;
  }
}

// ---- fused: [attention+proj+gated residual if gate!=0] + MFMA FFN + residual ----
// 512 threads (8 waves), __launch_bounds__(512,4): 4 waves/EU = 128 regs/wave
// TOTAL in the unified VGPR/AGPR file. Rounds 1-3 spilled because accumulators
// took 64 AGPR leaving only 64 arch. This version: 4 j-chunks of 128 so each
// wave owns 1 j-block per chunk -> acc1 = 16 AGPR, total AGPR 48, arch 80.
// sH is two ping-pong [64][128] halves so one barrier per chunk suffices
// (writer of half h at chunk ch races only with reader GEMM2(ch-2), which all
// waves completed before barrier(ch-1)).
// LDS 64 KB -> 2 blocks/CU = 16 waves/CU; grid 1024 = 2 clean rounds.
__global__ __launch_bounds__(512, 4) void fused_kernel(
    const float* __restrict__ feat, const float* __restrict__ qw,
    const float* __restrict__ qb, const float* __restrict__ projw,
    const float* __restrict__ projb, const float* __restrict__ ff1b,
    const float* __restrict__ ff2b, const u16* __restrict__ w1p,
    const u16* __restrict__ w2p, const float* __restrict__ gate,
    const float* __restrict__ ws_kv, float* __restrict__ out) {
  __shared__ u16 sX[64 * 256];  // feat/out1 tile [s][c], swizzled, 32 KB
  __shared__ u16 sH[2][64 * 128];  // ping-pong hidden half / attn buf, 32 KB

  int b = blockIdx.x >> 8;
  int s0 = (blockIdx.x & 255) * TSP;
  int tid = threadIdx.x;
  int w = tid >> 6;     // wave 0..7
  int lane = tid & 63;
  int lm = lane & 15, lq = lane >> 4;

  // ---- stage feat tile transposed: global [c][s] fp32 -> LDS [s][c] bf16 ----
  {
    const float* fb = feat + (((size_t)b * QC) << 14) + s0;
    int cq = (tid >> 4) * 4;   // c quad base 0..124
    int sq = (tid & 15) * 4;   // s quad
#pragma unroll
    for (int it = 0; it < 2; ++it) {
      int c = it * 128 + cq;
      float4 r0 = *(const float4*)(fb + ((size_t)(c + 0) << 14) + sq);
      float4 r1 = *(const float4*)(fb + ((size_t)(c + 1) << 14) + sq);
      float4 r2 = *(const float4*)(fb + ((size_t)(c + 2) << 14) + sq);
      float4 r3 = *(const float4*)(fb + ((size_t)(c + 3) << 14) + sq);
      uint2 d0, d1, d2, d3;
      d0.x = pk2(r0.x, r1.x); d0.y = pk2(r2.x, r3.x);
      d1.x = pk2(r0.y, r1.y); d1.y = pk2(r2.y, r3.y);
      d2.x = pk2(r0.z, r1.z); d2.y = pk2(r2.z, r3.z);
      d3.x = pk2(r0.w, r1.w); d3.y = pk2(r2.w, r3.w);
      *(uint2*)&sX[swz(sq + 0, c)] = d0;
      *(uint2*)&sX[swz(sq + 1, c)] = d1;
      *(uint2*)&sX[swz(sq + 2, c)] = d2;
      *(uint2*)&sX[swz(sq + 3, c)] = d3;
    }
  }
  float tg = tanhf(gate[0]);
  __syncthreads();

  if (tg != 0.0f) {
    if (w < 4) {
      // ---- Q for head w, spatial position `lane` ----
      float qreg[DH];
#pragma unroll
      for (int d = 0; d < DH; d++) {
        int o = w * DH + d;
        float a = qb[o];
        const float* qr = qw + (size_t)o * QC;
        for (int c = 0; c < QC; c += 4) {
          float4 wv = *(const float4*)(qr + c);
          a += b2f(sX[swz(lane, c + 0)]) * wv.x;
          a += b2f(sX[swz(lane, c + 1)]) * wv.y;
          a += b2f(sX[swz(lane, c + 2)]) * wv.z;
          a += b2f(sX[swz(lane, c + 3)]) * wv.w;
        }
        qreg[d] = a;
      }
      // ---- online-softmax attention over NT tokens ----
      const float* Kp = ws_kv + (size_t)(b * NH + w) * NT * DH;
      const float* Vp = Kp + NB * NH * NT * DH;
      float m_ = -1e30f, l_ = 0.f;
      float oacc[DH];
#pragma unroll
      for (int d = 0; d < DH; d++) oacc[d] = 0.f;
      const float scale = 0.17677669529663687f;  // 1/sqrt(32)
      for (int n = 0; n < NT; n++) {
        const float* kr = Kp + n * DH;
        float s = 0.f;
#pragma unroll
        for (int d = 0; d < DH; d++) s += qreg[d] * kr[d];
        s *= scale;
        float nm = fmaxf(m_, s);
        float p = __expf(s - nm);
        float al = __expf(m_ - nm);
        const float* vr = Vp + n * DH;
        l_ = l_ * al + p;
#pragma unroll
        for (int d = 0; d < DH; d++) oacc[d] = oacc[d] * al + p * vr[d];
        m_ = nm;
      }
      float inv = 1.0f / l_;
#pragma unroll
      for (int d = 0; d < DH; d++)
        sH[0][swzH(lane, w * DH + d)] = f2b(oacc[d] * inv);  // sattn [s][t=128]
    }
    __syncthreads();
    // ---- proj + gated residual into sX (wave w owns channels w*32..+32) ----
    for (int ci = 0; ci < 32; ci++) {
      int c = w * 32 + ci;
      float a = projb[c];
      const float* pr = projw + (size_t)c * TC;
      for (int t = 0; t < TC; t += 4) {
        float4 wv = *(const float4*)(pr + t);
        a += b2f(sH[0][swzH(lane, t + 0)]) * wv.x;
        a += b2f(sH[0][swzH(lane, t + 1)]) * wv.y;
        a += b2f(sH[0][swzH(lane, t + 2)]) * wv.z;
        a += b2f(sH[0][swzH(lane, t + 3)]) * wv.w;
      }
      float o1 = b2f(sX[swz(lane, c)]) + tg * a;
      sX[swz(lane, c)] = f2b(o1);
    }
    __syncthreads();
  }

  // ---- MFMA FFN; biases folded into accumulator init ----
  f32x4 acc2[2][4];  // [t = o-block][m = s-block], persists across chunks
#pragma unroll
  for (int t = 0; t < 2; t++) {
    float b2v = ff2b[(w * 2 + t) * 16 + lm];
    f32x4 iv = {b2v, b2v, b2v, b2v};
#pragma unroll
    for (int m = 0; m < 4; m++) acc2[t][m] = iv;
  }

#pragma unroll 1
  for (int ch = 0; ch < 4; ++ch) {
    u16* sHh = sH[ch & 1];
    // ---- GEMM1: wave owns j-block ch*8+w, K = 256 (8 k-steps) ----
    f32x4 acc1[4];
    {
      float b1v = ff1b[(ch * 8 + w) * 16 + lm];
      f32x4 iv = {b1v, b1v, b1v, b1v};
#pragma unroll
      for (int m = 0; m < 4; m++) acc1[m] = iv;
    }
    {
      const u16* p0 = w1p + (((size_t)(ch * 8 + w) * 8) * 64 + lane) * 8;
      // depth-2 rolling B pipeline (stride per k-step: 512 u16)
      bf16x8 c0 = *(const bf16x8*)(p0);
      bf16x8 n0 = *(const bf16x8*)(p0 + 512);
#pragma unroll
      for (int k = 0; k < 8; ++k) {
        bf16x8 f0;
        if (k < 6) f0 = *(const bf16x8*)(p0 + (size_t)(k + 2) * 512);
        int col = k * 32 + lq * 8;
#pragma unroll
        for (int m = 0; m < 4; m++) {
          bf16x8 a = *(const bf16x8*)&sX[swz(m * 16 + lm, col)];
          acc1[m] = __builtin_amdgcn_mfma_f32_16x16x32_bf16(a, c0, acc1[m], 0, 0, 0);
        }
        c0 = n0;
        if (k < 6) n0 = f0;
      }
    }
    // SiLU (bias already in acc) -> sHh[s][j_local]; safe pre-barrier:
    // only racing reader of this half is GEMM2(ch-2), done before barrier(ch-1)
    {
      int jl = w * 16 + lm;
#pragma unroll
      for (int m = 0; m < 4; m++) {
        int sb = m * 16 + lq * 4;
        f32x4 v = acc1[m];
#pragma unroll
        for (int r = 0; r < 4; r++) {
          float x = v[r];
          float sl = x * __builtin_amdgcn_rcpf(1.f + __expf(-x));
          sHh[swzH(sb + r, jl)] = f2b_fast(sl);
        }
      }
    }
    // GEMM2 first 2 k-step weights loaded BEFORE the barrier: latency hides
    const u16* qp0 = w2p + (((size_t)((w * 2) * 16 + ch * 4)) * 64 + lane) * 8;
    const u16* qp1 = qp0 + 8192;  // next o-block (16 kblks * 512)
    bf16x8 d0 = *(const bf16x8*)(qp0);
    bf16x8 d1 = *(const bf16x8*)(qp1);
    bf16x8 e0 = *(const bf16x8*)(qp0 + 512);
    bf16x8 e1 = *(const bf16x8*)(qp1 + 512);
    __syncthreads();  // sHh ready
    // ---- GEMM2 partial: K = this 128-j chunk (4 k-steps), o-blocks {2w,2w+1} ----
#pragma unroll
    for (int k = 0; k < 4; ++k) {
      bf16x8 f0, f1;
      if (k < 2) {
        f0 = *(const bf16x8*)(qp0 + (size_t)(k + 2) * 512);
        f1 = *(const bf16x8*)(qp1 + (size_t)(k + 2) * 512);
      }
      int col = k * 32 + lq * 8;
#pragma unroll
      for (int m = 0; m < 4; m++) {
        bf16x8 a = *(const bf16x8*)&sHh[swzH(m * 16 + lm, col)];
        acc2[0][m] = __builtin_amdgcn_mfma_f32_16x16x32_bf16(a, d0, acc2[0][m], 0, 0, 0);
        acc2[1][m] = __builtin_amdgcn_mfma_f32_16x16x32_bf16(a, d1, acc2[1][m], 0, 0, 0);
      }
      d0 = e0; d1 = e1;
      if (k < 2) { e0 = f0; e1 = f1; }
    }
  }

  // ---- epilogue: out[c][s] = out1 + ff (bias already in acc2) ----
#pragma unroll
  for (int t = 0; t < 2; t++) {
    int c = (w * 2 + t) * 16 + lm;
#pragma unroll
    for (int m = 0; m < 4; m++) {
      int sb = m * 16 + lq * 4;
      f32x4 v = acc2[t][m];
      float4 ov;
      ov.x = v[0] + b2f(sX[swz(sb + 0, c)]);
      ov.y = v[1] + b2f(sX[swz(sb + 1, c)]);
      ov.z = v[2] + b2f(sX[swz(sb + 2, c)]);
      ov.w = v[3] + b2f(sX[swz(sb + 3, c)]);
      *(float4*)(out + (((size_t)(b * QC + c)) << 14) + s0 + sb) = ov;
    }
  }
}

extern "C" void kernel_launch(void* const* d_in, const int* in_sizes, int n_in,
                              void* d_out, int out_size, void* d_ws, size_t ws_size,
                              hipStream_t stream) {
  const float* feat   = (const float*)d_in[0];
  const float* tokens = (const float*)d_in[1];
  const float* qw     = (const float*)d_in[2];
  const float* qb     = (const float*)d_in[3];
  const float* kw     = (const float*)d_in[4];
  const float* vw     = (const float*)d_in[5];
  const float* projw  = (const float*)d_in[6];
  const float* projb  = (const float*)d_in[7];
  const float* ff1w   = (const float*)d_in[8];
  const float* ff1b   = (const float*)d_in[9];
  const float* ff2w   = (const float*)d_in[10];
  const float* ff2b   = (const float*)d_in[11];
  const float* gate   = (const float*)d_in[12];
  float* out = (float*)d_out;

  u16* w1p = (u16*)d_ws;                               // 256 KB
  u16* w2p = w1p + 131072;                             // 256 KB
  float* ws_kv = (float*)((char*)d_ws + 524288);       // 1 MB (K then V)

  prep_kernel<<<dim3(NB * NT), dim3(256), 0, stream>>>(
      ff1w, ff2w, w1p, w2p, tokens, kw, vw, gate, ws_kv);
  fused_kernel<<<dim3(NB * (SD / TSP)), dim3(512), 0, stream>>>(
      feat, qw, qb, projw, projb, ff1b, ff2b, w1p, w2p, gate, ws_kv, out);
}